// Round 2
// baseline (561.490 us; speedup 1.0000x reference)
//
#include <hip/hip_runtime.h>
#include <hip/hip_bf16.h>
#include <stdint.h>

#define D_IN  4096
#define D_OUT 4096
#define MROWS 8192   // 2 * 4096 rows of x

using bf16x8 = __attribute__((ext_vector_type(8))) short;
using f32x4  = __attribute__((ext_vector_type(4))) float;

__device__ __forceinline__ unsigned short f2bf(float f) {
  union { float f; unsigned u; } a; a.f = f;
  // round-to-nearest-even fp32 -> bf16 (no NaN handling needed here)
  return (unsigned short)((a.u + 0x7FFFu + ((a.u >> 16) & 1u)) >> 16);
}

// -------- Kernel 1 (fused): RMSNorm -> bf16 xn  AND  w_q fp32 -> bf16 -----
// Blocks [0, MROWS): one block per row of x (RMSNorm).
// Blocks [MROWS, MROWS+8192): convert w_q, 8 floats (2x float4) per thread.
__global__ __launch_bounds__(256) void prep_kernel(
    const float* __restrict__ x, const float* __restrict__ nw,
    unsigned short* __restrict__ xn,
    const float* __restrict__ wq, unsigned short* __restrict__ wb) {
  const int b = blockIdx.x;
  const int t = threadIdx.x;

  if (b < MROWS) {
    // ---- RMSNorm on row b ----
    const float4* xr  = (const float4*)(x + (size_t)b * D_IN);
    const float4* nw4 = (const float4*)nw;

    float4 v[4];
    float ss = 0.f;
#pragma unroll
    for (int i = 0; i < 4; ++i) {
      v[i] = xr[i * 256 + t];
      ss += v[i].x * v[i].x + v[i].y * v[i].y + v[i].z * v[i].z + v[i].w * v[i].w;
    }
#pragma unroll
    for (int off = 32; off > 0; off >>= 1) ss += __shfl_down(ss, off, 64);

    __shared__ float red[4];
    if ((t & 63) == 0) red[t >> 6] = ss;
    __syncthreads();
    const float scale =
        rsqrtf((red[0] + red[1] + red[2] + red[3]) * (1.0f / D_IN) + 1e-6f);

    ushort4* out = (ushort4*)(xn + (size_t)b * D_IN);
#pragma unroll
    for (int i = 0; i < 4; ++i) {
      const float4 w = nw4[i * 256 + t];
      ushort4 o;
      o.x = f2bf(v[i].x * scale * w.x);
      o.y = f2bf(v[i].y * scale * w.y);
      o.z = f2bf(v[i].z * scale * w.z);
      o.w = f2bf(v[i].w * scale * w.w);
      out[i * 256 + t] = o;
    }
  } else {
    // ---- w_q conversion: 2 consecutive float4 per thread ----
    const int i0 = ((b - MROWS) * 256 + t) * 2;   // float4 index, < 4096*4096/4
    const float4* w4 = (const float4*)wq;
    ushort4* o4 = (ushort4*)wb;
#pragma unroll
    for (int u = 0; u < 2; ++u) {
      const float4 v = w4[i0 + u];
      ushort4 o;
      o.x = f2bf(v.x); o.y = f2bf(v.y); o.z = f2bf(v.z); o.w = f2bf(v.w);
      o4[i0 + u] = o;
    }
  }
}

// ---------------- Kernel 2: bf16 GEMM (A: MxK, B: NxK i.e. B^T), + gamma ---
// LDS layout is XOR-swizzled to kill ds_read_b128 bank conflicts:
//   16B chunk (row, j) lives at slot row*4 + (j ^ ((row>>1)&3)).
// global_load_lds forces LDS slot = lane order, so the swizzle is applied by
// permuting the *global source* chunk each lane fetches (legal: per-lane
// global addresses are unconstrained), and compensated in the ds_read offset.
#define BM 128
#define BN 128
#define BK 32

__global__ __launch_bounds__(256) void gemm_kernel(
    const unsigned short* __restrict__ A,   // MROWS x D_IN bf16
    const unsigned short* __restrict__ B,   // D_OUT x D_IN bf16 (N-major, K-contig)
    const float* __restrict__ gamma,        // D_OUT
    float* __restrict__ C) {                // MROWS x D_OUT fp32
  __shared__ short sA[BM * BK];  // 8 KB
  __shared__ short sB[BN * BK];  // 8 KB

  const int tid  = threadIdx.x;
  const int lane = tid & 63;
  const int wv   = tid >> 6;
  const int wm   = wv & 1;        // 2x2 wave grid, each wave owns 64x64
  const int wn   = wv >> 1;

  // Grouped block swizzle for L2 locality: 16 bm x 32 bn panels.
  const int pid = blockIdx.x;                 // 0..2047
  const int NUM_BN = D_OUT / BN;              // 32
  const int GROUP = 16;
  const int group_span = GROUP * NUM_BN;      // 512
  const int gid = pid / group_span;
  const int bm = gid * GROUP + (pid % GROUP);
  const int bn = (pid % group_span) / GROUP;

  f32x4 acc[4][4];
#pragma unroll
  for (int i = 0; i < 4; ++i)
#pragma unroll
    for (int j = 0; j < 4; ++j) acc[i][j] = (f32x4){0.f, 0.f, 0.f, 0.f};

  const size_t aBase = (size_t)(bm * BM) * D_IN;
  const size_t bBase = (size_t)(bn * BN) * D_IN;

  // Per-thread staging constants: chunk c -> row r, swizzled k-offset cc.
  // (slot index == c by construction: lds dest = region base + lane*16)
  int rA[2], ccA[2];
#pragma unroll
  for (int i = 0; i < 2; ++i) {
    const int c = i * 256 + tid;
    rA[i] = c >> 2;
    ccA[i] = (((c & 3) ^ ((rA[i] >> 1) & 3))) * 8;
  }

  for (int k0 = 0; k0 < D_IN; k0 += BK) {
#pragma unroll
    for (int i = 0; i < 2; ++i) {
      __builtin_amdgcn_global_load_lds(
          (__attribute__((address_space(1))) void*)(A + aBase + (size_t)rA[i] * D_IN + k0 + ccA[i]),
          (__attribute__((address_space(3))) void*)&sA[(i * 256 + wv * 64) * 8],
          16, 0, 0);
    }
#pragma unroll
    for (int i = 0; i < 2; ++i) {
      __builtin_amdgcn_global_load_lds(
          (__attribute__((address_space(1))) void*)(B + bBase + (size_t)rA[i] * D_IN + k0 + ccA[i]),
          (__attribute__((address_space(3))) void*)&sB[(i * 256 + wv * 64) * 8],
          16, 0, 0);
    }
    __syncthreads();   // compiler emits s_waitcnt vmcnt(0) before s_barrier

    bf16x8 af[4], bfr[4];
    const int m0 = wm * 64 + (lane & 15);
    const int n0 = wn * 64 + (lane & 15);
    // swizzle compensation: (row>>1)&3 == (lane>>1)&3 because the row base
    // (wm*64 + i*16) is a multiple of 16
    const int kk = (((lane >> 4) ^ ((lane >> 1) & 3))) * 8;
#pragma unroll
    for (int i = 0; i < 4; ++i) af[i]  = *(const bf16x8*)&sA[(m0 + i * 16) * BK + kk];
#pragma unroll
    for (int j = 0; j < 4; ++j) bfr[j] = *(const bf16x8*)&sB[(n0 + j * 16) * BK + kk];

#pragma unroll
    for (int i = 0; i < 4; ++i)
#pragma unroll
      for (int j = 0; j < 4; ++j)
        acc[i][j] = __builtin_amdgcn_mfma_f32_16x16x32_bf16(af[i], bfr[j], acc[i][j], 0, 0, 0);

    __syncthreads();
  }

  // Epilogue: C/D layout col = lane&15, row = (lane>>4)*4 + reg. Fuse gamma.
  const int col0 = bn * BN + wn * 64 + (lane & 15);
  const int row0 = bm * BM + wm * 64 + ((lane >> 4) * 4);
#pragma unroll
  for (int j = 0; j < 4; ++j) {
    const float g = gamma[col0 + j * 16];
#pragma unroll
    for (int i = 0; i < 4; ++i) {
      const int rb = row0 + i * 16;
#pragma unroll
      for (int r = 0; r < 4; ++r) {
        C[(size_t)(rb + r) * D_OUT + (col0 + j * 16)] = acc[i][j][r] * g;
      }
    }
  }
}

extern "C" void kernel_launch(void* const* d_in, const int* in_sizes, int n_in,
                              void* d_out, int out_size, void* d_ws, size_t ws_size,
                              hipStream_t stream) {
  const float* x     = (const float*)d_in[0];  // (2,4096,4096)
  const float* nw    = (const float*)d_in[1];  // (4096,)
  const float* wq    = (const float*)d_in[2];  // (4096,4096) {-1,0,1}
  const float* gamma = (const float*)d_in[3];  // (4096,)
  float* y = (float*)d_out;

  // Workspace layout: xn bf16 (64 MB) | wq bf16 (32 MB)  => 96 MB total
  unsigned short* xn = (unsigned short*)d_ws;
  unsigned short* wb = xn + (size_t)MROWS * D_IN;

  // 8192 rmsnorm blocks + 8192 cvt blocks in one dispatch
  prep_kernel<<<MROWS + 8192, 256, 0, stream>>>(x, nw, xn, wq, wb);

  gemm_kernel<<<(MROWS / BM) * (D_OUT / BN), 256, 0, stream>>>(xn, wb, gamma, y);
}

// Round 3
// 428.270 us; speedup vs baseline: 1.3111x; 1.3111x over previous
//
#include <hip/hip_runtime.h>
#include <hip/hip_bf16.h>
#include <stdint.h>

#define D_IN  4096
#define D_OUT 4096
#define MROWS 8192   // 2 * 4096 rows of x

using i32x4 = __attribute__((ext_vector_type(4))) int;

// -------- Kernel 1 (fused): RMSNorm -> i8 xn (per-row absmax scale)
//          AND w_q fp32 -> i8 (exact, values in {-1,0,1}) ------------------
// Blocks [0, MROWS): one block per row of x.
// Blocks [MROWS, MROWS+4096): convert w_q, 16 floats per thread, coalesced.
__global__ __launch_bounds__(256) void prep_kernel(
    const float* __restrict__ x, const float* __restrict__ nw,
    signed char* __restrict__ xq, float* __restrict__ srow,
    const float* __restrict__ wq, signed char* __restrict__ wb) {
  const int b = blockIdx.x;
  const int t = threadIdx.x;

  if (b < MROWS) {
    const float4* xr  = (const float4*)(x + (size_t)b * D_IN);
    const float4* nw4 = (const float4*)nw;

    float4 p[4];
    float ss = 0.f, mx = 0.f;
#pragma unroll
    for (int i = 0; i < 4; ++i) {
      const float4 v = xr[i * 256 + t];
      const float4 w = nw4[i * 256 + t];
      ss += v.x * v.x + v.y * v.y + v.z * v.z + v.w * v.w;
      p[i].x = v.x * w.x; p[i].y = v.y * w.y;
      p[i].z = v.z * w.z; p[i].w = v.w * w.w;
      mx = fmaxf(mx, fmaxf(fmaxf(fabsf(p[i].x), fabsf(p[i].y)),
                           fmaxf(fabsf(p[i].z), fabsf(p[i].w))));
    }
#pragma unroll
    for (int off = 32; off > 0; off >>= 1) {
      ss += __shfl_down(ss, off, 64);
      mx = fmaxf(mx, __shfl_down(mx, off, 64));
    }

    __shared__ float rs[4], rm[4];
    if ((t & 63) == 0) { rs[t >> 6] = ss; rm[t >> 6] = mx; }
    __syncthreads();
    const float scale =
        rsqrtf((rs[0] + rs[1] + rs[2] + rs[3]) * (1.0f / D_IN) + 1e-6f);
    const float rowmax = fmaxf(fmaxf(rm[0], rm[1]), fmaxf(rm[2], rm[3])) * scale;
    const float s   = fmaxf(rowmax, 1e-20f) * (1.0f / 127.0f);
    const float f   = scale / s;   // = scale * 127 / rowmax
    if (t == 0) srow[b] = s;

    int* out = (int*)(xq + (size_t)b * D_IN);
#pragma unroll
    for (int i = 0; i < 4; ++i) {
      const int q0 = (int)rintf(p[i].x * f);
      const int q1 = (int)rintf(p[i].y * f);
      const int q2 = (int)rintf(p[i].z * f);
      const int q3 = (int)rintf(p[i].w * f);
      out[i * 256 + t] =
          (q0 & 0xFF) | ((q1 & 0xFF) << 8) | ((q2 & 0xFF) << 16) | (q3 << 24);
    }
  } else {
    // ---- w_q conversion, fully coalesced: float4 idx cb*1024 + i*256 + t --
    const int cb = b - MROWS;
    const float4* w4 = (const float4*)wq;
    int* o = (int*)wb;
#pragma unroll
    for (int i = 0; i < 4; ++i) {
      const int idx = cb * 1024 + i * 256 + t;
      const float4 v = w4[idx];
      const int q0 = (int)v.x, q1 = (int)v.y, q2 = (int)v.z, q3 = (int)v.w;
      o[idx] = (q0 & 0xFF) | ((q1 & 0xFF) << 8) | ((q2 & 0xFF) << 16) | (q3 << 24);
    }
  }
}

// ---------------- Kernel 2: i8 GEMM (A: MxK, B: NxK i.e. B^T) -------------
// mfma_i32_16x16x64_i8: per lane A[m=lane&15][k=(lane>>4)*16 + j], j in [0,16)
// (16 consecutive i8 = 16 B = 4 VGPRs; same 16B/lane pattern as bf16 x8).
// C/D layout is shape-determined: col=lane&15, row=(lane>>4)*4+reg.
// LDS XOR-swizzle (proven 0 conflicts in round 2): 16B chunk (row, j) lives
// at slot j ^ ((row>>1)&3); applied by permuting the *global source* chunk
// (global_load_lds forces LDS slot = lane order), compensated in ds_read.
#define BM 128
#define BN 128
#define BKB 64   // K per tile, in i8 elements == bytes

__global__ __launch_bounds__(256) void gemm_kernel(
    const signed char* __restrict__ A,   // MROWS x D_IN i8
    const signed char* __restrict__ B,   // D_OUT x D_IN i8
    const float* __restrict__ srow,      // MROWS   (per-row dequant scale)
    const float* __restrict__ gamma,     // D_OUT
    float* __restrict__ C) {             // MROWS x D_OUT fp32
  __shared__ __align__(16) signed char sA[BM * BKB];  // 8 KB
  __shared__ __align__(16) signed char sB[BN * BKB];  // 8 KB

  const int tid  = threadIdx.x;
  const int lane = tid & 63;
  const int wv   = tid >> 6;
  const int wm   = wv & 1;        // 2x2 wave grid, each wave owns 64x64
  const int wn   = wv >> 1;
  const int bn   = blockIdx.x;    // plain raster (round-1 cfg: lowest FETCH)
  const int bm   = blockIdx.y;

  i32x4 acc[4][4];
#pragma unroll
  for (int i = 0; i < 4; ++i)
#pragma unroll
    for (int j = 0; j < 4; ++j) acc[i][j] = (i32x4){0, 0, 0, 0};

  const size_t aBase = (size_t)(bm * BM) * D_IN;
  const size_t bBase = (size_t)(bn * BN) * D_IN;

  // chunk c = i*256+tid -> tile row r, swizzled k-byte offset cc
  int r_[2], cc_[2];
#pragma unroll
  for (int i = 0; i < 2; ++i) {
    const int c = i * 256 + tid;
    r_[i]  = c >> 2;
    cc_[i] = ((c & 3) ^ ((r_[i] >> 1) & 3)) * 16;
  }

  for (int k0 = 0; k0 < D_IN; k0 += BKB) {
#pragma unroll
    for (int i = 0; i < 2; ++i) {
      __builtin_amdgcn_global_load_lds(
          (__attribute__((address_space(1))) void*)(A + aBase + (size_t)r_[i] * D_IN + k0 + cc_[i]),
          (__attribute__((address_space(3))) void*)&sA[(i * 256 + wv * 64) * 16],
          16, 0, 0);
    }
#pragma unroll
    for (int i = 0; i < 2; ++i) {
      __builtin_amdgcn_global_load_lds(
          (__attribute__((address_space(1))) void*)(B + bBase + (size_t)r_[i] * D_IN + k0 + cc_[i]),
          (__attribute__((address_space(3))) void*)&sB[(i * 256 + wv * 64) * 16],
          16, 0, 0);
    }
    __syncthreads();

    i32x4 af[4], bfr[4];
    const int m0 = wm * 64 + (lane & 15);
    const int n0 = wn * 64 + (lane & 15);
    // swizzle compensation: (row>>1)&3 == (lane>>1)&3 (row base mult. of 16)
    const int kk = (((lane >> 4) ^ ((lane >> 1) & 3))) * 16;
#pragma unroll
    for (int i = 0; i < 4; ++i) af[i]  = *(const i32x4*)&sA[(m0 + i * 16) * BKB + kk];
#pragma unroll
    for (int j = 0; j < 4; ++j) bfr[j] = *(const i32x4*)&sB[(n0 + j * 16) * BKB + kk];

#pragma unroll
    for (int i = 0; i < 4; ++i)
#pragma unroll
      for (int j = 0; j < 4; ++j)
        acc[i][j] = __builtin_amdgcn_mfma_i32_16x16x64_i8(af[i], bfr[j], acc[i][j], 0, 0, 0);

    __syncthreads();
  }

  // Epilogue: y = acc * srow[row] * gamma[col]
  const int col0 = bn * BN + wn * 64 + (lane & 15);
  const int row0 = bm * BM + wm * 64 + ((lane >> 4) * 4);
  float sr[4][4];
#pragma unroll
  for (int i = 0; i < 4; ++i)
#pragma unroll
    for (int r = 0; r < 4; ++r) sr[i][r] = srow[row0 + i * 16 + r];

#pragma unroll
  for (int j = 0; j < 4; ++j) {
    const float g = gamma[col0 + j * 16];
#pragma unroll
    for (int i = 0; i < 4; ++i) {
      const int rb = row0 + i * 16;
#pragma unroll
      for (int r = 0; r < 4; ++r) {
        C[(size_t)(rb + r) * D_OUT + (col0 + j * 16)] =
            (float)acc[i][j][r] * sr[i][r] * g;
      }
    }
  }
}

extern "C" void kernel_launch(void* const* d_in, const int* in_sizes, int n_in,
                              void* d_out, int out_size, void* d_ws, size_t ws_size,
                              hipStream_t stream) {
  const float* x     = (const float*)d_in[0];  // (2,4096,4096)
  const float* nw    = (const float*)d_in[1];  // (4096,)
  const float* wq    = (const float*)d_in[2];  // (4096,4096) {-1,0,1}
  const float* gamma = (const float*)d_in[3];  // (4096,)
  float* y = (float*)d_out;

  // Workspace: xq i8 (32 MB) | wb i8 (16 MB) | srow fp32 (32 KB)
  signed char* xq = (signed char*)d_ws;
  signed char* wb = xq + (size_t)MROWS * D_IN;
  float* srow = (float*)(wb + (size_t)D_OUT * D_IN);

  // 8192 rmsnorm blocks + 4096 cvt blocks in one dispatch
  prep_kernel<<<MROWS + 4096, 256, 0, stream>>>(x, nw, xq, srow, wq, wb);

  gemm_kernel<<<dim3(D_OUT / BN, MROWS / BM), 256, 0, stream>>>(xq, wb, srow, gamma, y);
}